// Round 1
// baseline (516.622 us; speedup 1.0000x reference)
//
#include <hip/hip_runtime.h>
#include <hip/hip_bf16.h>

// Problem constants (match reference)
#define V  400000
#define D  200
#define C  45
#define B  32
#define S  128
#define KN 12
#define KC 10
#define KT (KN + KC)   // 22 total feature slots

#define STILE 32       // s-tile per logit block

// ---------------------------------------------------------------------------
// Kernel 1: masked-mean embedding gather  ->  feat [B*S, D] (f32, in d_ws)
// One block per (b,s) row. Threads 0..199 each own one d.
// ---------------------------------------------------------------------------
__global__ __launch_bounds__(256) void feat_kernel(
    const int* __restrict__ ng_ids, const int* __restrict__ ng_mask,
    const int* __restrict__ cx_ids, const int* __restrict__ cx_mask,
    const float* __restrict__ embed, float* __restrict__ feat)
{
    const int row = blockIdx.x;          // [0, B*S)
    const int tid = threadIdx.x;

    __shared__ int   s_ids[KT];          // id, or -1 when masked out
    __shared__ float s_inv;              // 1 / max(cnt, 1)

    if (tid < KN) {
        int m = ng_mask[row * KN + tid];
        s_ids[tid] = m ? ng_ids[row * KN + tid] : -1;
    } else if (tid < KT) {
        int k = tid - KN;
        int m = cx_mask[row * KC + k];
        s_ids[tid] = m ? cx_ids[row * KC + k] : -1;
    }
    __syncthreads();
    if (tid == 0) {
        int cnt = 0;
        #pragma unroll
        for (int i = 0; i < KT; ++i) cnt += (s_ids[i] >= 0);
        s_inv = 1.0f / (float)(cnt > 0 ? cnt : 1);
    }
    __syncthreads();

    const float inv = s_inv;
    for (int d = tid; d < D; d += 256) {
        float acc = 0.0f;
        #pragma unroll
        for (int i = 0; i < KT; ++i) {
            int id = s_ids[i];                 // wave-uniform branch
            if (id >= 0) acc += embed[(long long)id * D + d];
        }
        feat[(long long)row * D + d] = acc * inv;
    }
}

// ---------------------------------------------------------------------------
// Kernel 2: 5-word-window linear layer.
// Block = (b, 32-row s-tile). Stage 36 feat rows (incl. 2-halo each side,
// zero outside [0,S)) in LDS, then each thread computes ~6 outputs
// (length-1000 dot products, float4 both sides).
// ---------------------------------------------------------------------------
__global__ __launch_bounds__(256) void logit_kernel(
    const float* __restrict__ feat, const float* __restrict__ W,
    const float* __restrict__ bias, float* __restrict__ out)
{
    const int blk  = blockIdx.x;
    const int nst  = S / STILE;            // s-tiles per batch
    const int b    = blk / nst;
    const int st   = (blk % nst) * STILE;  // first global s of tile
    const int tid  = threadIdx.x;

    __shared__ float lfeat[(STILE + 4) * D];   // 36*200*4 = 28.8 KB

    // Load halo'd feat rows: global s in [st-2, st+STILE+2)
    for (int i = tid; i < (STILE + 4) * D; i += 256) {
        int r = i / D;
        int d = i - r * D;
        int s = st - 2 + r;
        lfeat[i] = (s >= 0 && s < S) ? feat[((long long)b * S + s) * D + d]
                                     : 0.0f;
    }
    __syncthreads();

    for (int o = tid; o < STILE * C; o += 256) {
        int sl = o / C;                    // local s within tile
        int c  = o - sl * C;
        float acc = bias[c];
        const float* wr = W + (long long)c * 5 * D;
        #pragma unroll
        for (int w = 0; w < 5; ++w) {
            const float* fr = &lfeat[(sl + w) * D];   // global s + w - 2
            const float* wp = wr + w * D;
            for (int d = 0; d < D; d += 4) {
                float4 f  = *(const float4*)&fr[d];
                float4 wv = *(const float4*)&wp[d];
                acc += f.x * wv.x + f.y * wv.y + f.z * wv.z + f.w * wv.w;
            }
        }
        out[((long long)b * S + st + sl) * C + c] = acc;
    }
}

// ---------------------------------------------------------------------------
extern "C" void kernel_launch(void* const* d_in, const int* in_sizes, int n_in,
                              void* d_out, int out_size, void* d_ws, size_t ws_size,
                              hipStream_t stream)
{
    const int*   ng_ids  = (const int*)  d_in[0];
    const int*   ng_mask = (const int*)  d_in[1];
    const int*   cx_ids  = (const int*)  d_in[2];
    const int*   cx_mask = (const int*)  d_in[3];
    const float* embed   = (const float*)d_in[4];
    const float* W       = (const float*)d_in[5];
    const float* bias    = (const float*)d_in[6];
    float*       out     = (float*)d_out;

    float* feat = (float*)d_ws;            // B*S*D f32 = 3.28 MB

    feat_kernel<<<B * S, 256, 0, stream>>>(ng_ids, ng_mask, cx_ids, cx_mask,
                                           embed, feat);
    logit_kernel<<<B * (S / STILE), 256, 0, stream>>>(feat, W, bias, out);
}

// Round 2
// 422.684 us; speedup vs baseline: 1.2222x; 1.2222x over previous
//
#include <hip/hip_runtime.h>
#include <hip/hip_bf16.h>

// Problem constants (match reference)
#define V  400000
#define D  200
#define DQ (D / 4)      // 50 float4 per embedding row
#define C  45
#define B  32
#define S  128
#define KN 12
#define KC 10
#define KT (KN + KC)    // 22 feature slots

#define STILE 16        // s rows per logit block
#define NQ (STILE / 4)  // 4 quad-groups
#define CT 48           // c-threads per quad group (45 padded to 48)
#define LT (STILE + 4)  // staged rows incl. 2-halo each side

// ---------------------------------------------------------------------------
// Kernel 1: masked-mean embedding gather -> feat [B*S, D] f32 (in d_ws).
// One WAVE per (b,s) row. Lanes 0..21 fetch ids+masks; ids broadcast via
// readlane (wave-uniform branches skip masked ids -> half the HBM traffic);
// lanes 0..49 gather the 800B row as float4, two ids in flight at a time.
// ---------------------------------------------------------------------------
__global__ __launch_bounds__(256) void feat_kernel(
    const int* __restrict__ ng_ids, const int* __restrict__ ng_mask,
    const int* __restrict__ cx_ids, const int* __restrict__ cx_mask,
    const float* __restrict__ embed, float* __restrict__ feat)
{
    const int lane = threadIdx.x & 63;
    const int row  = blockIdx.x * 4 + (threadIdx.x >> 6);   // [0, B*S)

    int id = -1;
    if (lane < KN) {
        if (ng_mask[row * KN + lane]) id = ng_ids[row * KN + lane];
    } else if (lane < KT) {
        const int k = lane - KN;
        if (cx_mask[row * KC + k]) id = cx_ids[row * KC + k];
    }
    const unsigned long long bal = __ballot(id >= 0);
    const int cnt = __popcll(bal);
    const float inv = 1.0f / (float)(cnt > 0 ? cnt : 1);

    if (lane < DQ) {
        float4 acc0 = make_float4(0.f, 0.f, 0.f, 0.f);
        float4 acc1 = make_float4(0.f, 0.f, 0.f, 0.f);
        #pragma unroll
        for (int i = 0; i < KT; i += 2) {
            const int idA = __builtin_amdgcn_readlane(id, i);
            const int idB = __builtin_amdgcn_readlane(id, i + 1);
            float4 t0 = make_float4(0.f, 0.f, 0.f, 0.f);
            float4 t1 = make_float4(0.f, 0.f, 0.f, 0.f);
            if (idA >= 0)   // wave-uniform (SGPR) branch
                t0 = ((const float4*)(embed + (size_t)idA * D))[lane];
            if (idB >= 0)
                t1 = ((const float4*)(embed + (size_t)idB * D))[lane];
            acc0.x += t0.x; acc0.y += t0.y; acc0.z += t0.z; acc0.w += t0.w;
            acc1.x += t1.x; acc1.y += t1.y; acc1.z += t1.z; acc1.w += t1.w;
        }
        float4 r;
        r.x = (acc0.x + acc1.x) * inv;
        r.y = (acc0.y + acc1.y) * inv;
        r.z = (acc0.z + acc1.z) * inv;
        r.w = (acc0.w + acc1.w) * inv;
        ((float4*)(feat + (size_t)row * D))[lane] = r;
    }
}

// ---------------------------------------------------------------------------
// Kernel 2: 5-word-window linear. Block = (b, 16-row s-tile), 192 threads.
// Thread = (c, quad q): owns outputs {st+4q..st+4q+3} for class c.
// Per dq step: 5 W float4 (L1-resident, c-coalesced) + 8 LDS float4
// (2-way broadcast, conflict-free) feed 80 FMAs.
// ---------------------------------------------------------------------------
__global__ __launch_bounds__(192) void logit_kernel(
    const float* __restrict__ feat, const float* __restrict__ W,
    const float* __restrict__ bias, float* __restrict__ out)
{
    const int b   = blockIdx.x >> 3;          // S/STILE = 8 tiles per batch
    const int st  = (blockIdx.x & 7) * STILE;
    const int tid = threadIdx.x;

    __shared__ float4 lf[LT * DQ];            // 20*50*16 = 16 KB

    const float4* feat4 = (const float4*)feat;
    for (int i = tid; i < LT * DQ; i += 192) {
        const int r  = i / DQ;
        const int dq = i - r * DQ;
        const int s  = st - 2 + r;
        float4 v = make_float4(0.f, 0.f, 0.f, 0.f);
        if (s >= 0 && s < S) v = feat4[(b * S + s) * DQ + dq];
        lf[i] = v;
    }
    __syncthreads();

    const int c = tid % CT;                   // 0..47
    const int q = tid / CT;                   // 0..3
    const bool cvalid = (c < C);
    const int cc = cvalid ? c : (C - 1);

    const float4* W4 = (const float4*)W;      // [C][5][DQ] float4
    const float4* wbase = W4 + (size_t)cc * (5 * DQ);

    float acc[4] = {0.f, 0.f, 0.f, 0.f};

    for (int dq = 0; dq < DQ; ++dq) {
        float4 wv[5];
        #pragma unroll
        for (int w = 0; w < 5; ++w) wv[w] = wbase[w * DQ + dq];
        float4 fr[8];
        #pragma unroll
        for (int j = 0; j < 8; ++j) fr[j] = lf[(q * 4 + j) * DQ + dq];
        #pragma unroll
        for (int k = 0; k < 4; ++k) {
            #pragma unroll
            for (int w = 0; w < 5; ++w) {
                acc[k] += fr[k + w].x * wv[w].x + fr[k + w].y * wv[w].y
                        + fr[k + w].z * wv[w].z + fr[k + w].w * wv[w].w;
            }
        }
    }

    if (cvalid) {
        const float bv = bias[c];
        #pragma unroll
        for (int k = 0; k < 4; ++k) {
            const int s = st + q * 4 + k;
            out[((size_t)(b * S + s)) * C + c] = acc[k] + bv;
        }
    }
}

// ---------------------------------------------------------------------------
extern "C" void kernel_launch(void* const* d_in, const int* in_sizes, int n_in,
                              void* d_out, int out_size, void* d_ws, size_t ws_size,
                              hipStream_t stream)
{
    const int*   ng_ids  = (const int*)  d_in[0];
    const int*   ng_mask = (const int*)  d_in[1];
    const int*   cx_ids  = (const int*)  d_in[2];
    const int*   cx_mask = (const int*)  d_in[3];
    const float* embed   = (const float*)d_in[4];
    const float* W       = (const float*)d_in[5];
    const float* bias    = (const float*)d_in[6];
    float*       out     = (float*)d_out;

    float* feat = (float*)d_ws;               // B*S*D f32 = 3.28 MB

    feat_kernel<<<(B * S) / 4, 256, 0, stream>>>(ng_ids, ng_mask, cx_ids,
                                                 cx_mask, embed, feat);
    logit_kernel<<<B * (S / STILE), 192, 0, stream>>>(feat, W, bias, out);
}

// Round 3
// 409.648 us; speedup vs baseline: 1.2611x; 1.0318x over previous
//
#include <hip/hip_runtime.h>
#include <hip/hip_bf16.h>

// Problem constants (match reference)
#define V  400000
#define D  200
#define DQ (D / 4)      // 50 float4 per embedding row
#define C  45
#define B  32
#define S  128
#define KN 12
#define KC 10
#define KT (KN + KC)    // 22 feature slots

#define STILE 16        // s rows per block
#define LT (STILE + 4)  // staged rows incl. 2-halo each side = 20
#define RPW (LT / 4)    // rows gathered per wave = 5

// ---------------------------------------------------------------------------
// Fused kernel. Block = (b, 16-row s-tile), 256 threads = 4 waves.
// Phase 1: each wave gathers 5 feat rows (masked-mean over 22 embedding rows)
//          into LDS. Branchless: masked ids load row 0 (L2-hit) weighted 0 by
//          the ballot bit, so all 22 float4 loads pipeline with one HBM
//          latency instead of 11 serialized ones.
// Phase 2: thread (c=lane, quad=wave) computes 4 s-outputs for class c.
//          LDS reads are wave-broadcast; W working set (28.8 KB) is
//          L1-resident; out writes are c-coalesced.
// ---------------------------------------------------------------------------
__global__ __launch_bounds__(256) void fused_kernel(
    const int* __restrict__ ng_ids, const int* __restrict__ ng_mask,
    const int* __restrict__ cx_ids, const int* __restrict__ cx_mask,
    const float* __restrict__ embed, const float* __restrict__ W,
    const float* __restrict__ bias, float* __restrict__ out)
{
    const int b    = blockIdx.x >> 3;           // S/STILE = 8 tiles per batch
    const int st   = (blockIdx.x & 7) * STILE;
    const int tid  = threadIdx.x;
    const int wave = tid >> 6;
    const int lane = tid & 63;

    __shared__ float4 lf[LT * DQ];              // 20*50*16 = 16 KB

    // ---- Phase 1a: prefetch ids/masks for this wave's 5 rows ----
    int                ids[RPW];
    unsigned long long bal[RPW];
    float              inv[RPW];
    #pragma unroll
    for (int r = 0; r < RPW; ++r) {
        const int s = st - 2 + (wave * RPW + r);
        int id = -1;
        if (s >= 0 && s < S) {                  // wave-uniform
            const int row = b * S + s;
            if (lane < KN) {
                if (ng_mask[row * KN + lane]) id = ng_ids[row * KN + lane];
            } else if (lane < KT) {
                const int k = lane - KN;
                if (cx_mask[row * KC + k]) id = cx_ids[row * KC + k];
            }
        }
        bal[r] = __ballot(id >= 0);
        ids[r] = (id >= 0) ? id : 0;
        const int cnt = __popcll(bal[r]);
        inv[r] = 1.0f / (float)(cnt > 0 ? cnt : 1);  // empty/invalid rows: acc=0 anyway
    }

    // ---- Phase 1b: branchless pipelined gather, 5 rows -> LDS ----
    if (lane < DQ) {
        #pragma unroll
        for (int r = 0; r < RPW; ++r) {
            float4 a0 = make_float4(0.f, 0.f, 0.f, 0.f);
            float4 a1 = make_float4(0.f, 0.f, 0.f, 0.f);
            #pragma unroll
            for (int i = 0; i < KT; i += 2) {
                const int   iA = __builtin_amdgcn_readlane(ids[r], i);
                const int   iB = __builtin_amdgcn_readlane(ids[r], i + 1);
                const float wA = (float)((bal[r] >> i) & 1ULL);
                const float wB = (float)((bal[r] >> (i + 1)) & 1ULL);
                const float4 tA = ((const float4*)(embed + (size_t)iA * D))[lane];
                const float4 tB = ((const float4*)(embed + (size_t)iB * D))[lane];
                a0.x += tA.x * wA; a0.y += tA.y * wA;
                a0.z += tA.z * wA; a0.w += tA.w * wA;
                a1.x += tB.x * wB; a1.y += tB.y * wB;
                a1.z += tB.z * wB; a1.w += tB.w * wB;
            }
            float4 rv;
            rv.x = (a0.x + a1.x) * inv[r];
            rv.y = (a0.y + a1.y) * inv[r];
            rv.z = (a0.z + a1.z) * inv[r];
            rv.w = (a0.w + a1.w) * inv[r];
            lf[(wave * RPW + r) * DQ + lane] = rv;
        }
    }
    __syncthreads();

    // ---- Phase 2: windowed linear ----
    const int c = lane;                          // class per lane
    const int q = wave;                          // quad of 4 s-rows per wave
    if (c < C) {
        const float4* wbase = (const float4*)W + (size_t)c * (5 * DQ);
        float acc[4] = {0.f, 0.f, 0.f, 0.f};

        #pragma unroll 2
        for (int dq = 0; dq < DQ; ++dq) {
            float4 wv[5];
            #pragma unroll
            for (int w = 0; w < 5; ++w) wv[w] = wbase[w * DQ + dq];
            float4 fr[8];
            #pragma unroll
            for (int j = 0; j < 8; ++j) fr[j] = lf[(q * 4 + j) * DQ + dq];
            #pragma unroll
            for (int k = 0; k < 4; ++k) {
                #pragma unroll
                for (int w = 0; w < 5; ++w) {
                    acc[k] += fr[k + w].x * wv[w].x + fr[k + w].y * wv[w].y
                            + fr[k + w].z * wv[w].z + fr[k + w].w * wv[w].w;
                }
            }
        }

        const float bv = bias[c];
        #pragma unroll
        for (int k = 0; k < 4; ++k) {
            const int s = st + q * 4 + k;
            out[((size_t)(b * S + s)) * C + c] = acc[k] + bv;
        }
    }
}

// ---------------------------------------------------------------------------
extern "C" void kernel_launch(void* const* d_in, const int* in_sizes, int n_in,
                              void* d_out, int out_size, void* d_ws, size_t ws_size,
                              hipStream_t stream)
{
    const int*   ng_ids  = (const int*)  d_in[0];
    const int*   ng_mask = (const int*)  d_in[1];
    const int*   cx_ids  = (const int*)  d_in[2];
    const int*   cx_mask = (const int*)  d_in[3];
    const float* embed   = (const float*)d_in[4];
    const float* W       = (const float*)d_in[5];
    const float* bias    = (const float*)d_in[6];
    float*       out     = (float*)d_out;

    fused_kernel<<<B * (S / STILE), 256, 0, stream>>>(ng_ids, ng_mask, cx_ids,
                                                      cx_mask, embed, W, bias,
                                                      out);
}